// Round 1
// baseline (1103.299 us; speedup 1.0000x reference)
//
#include <hip/hip_runtime.h>
#include <cstdint>
#include <cstddef>

// B=2, H=16, S=2048, D=64. fp32 inputs (Q,K,V), int mask (width auto-detected),
// fp32 outputs: [context (4.19M) | attn_prob (134.2M)] concatenated.
#define S_LEN 2048
#define D_HEAD 64
#define NBH 32

typedef __attribute__((ext_vector_type(8))) short short8;
typedef __attribute__((ext_vector_type(8))) unsigned short ushort8;
typedef __attribute__((ext_vector_type(4))) unsigned short us4;
typedef __attribute__((ext_vector_type(4))) unsigned int ui4;
typedef __attribute__((ext_vector_type(4))) float floatx4;

__device__ __forceinline__ unsigned short f2bf(float f){
  union { float f; unsigned int i; } v; v.f = f;
  unsigned int u = v.i;
  u += 0x7fffu + ((u >> 16) & 1u);     // RNE
  return (unsigned short)(u >> 16);
}
__device__ __forceinline__ float bf2f(unsigned short u){
  union { unsigned int i; float f; } v; v.i = ((unsigned int)u) << 16; return v.f;
}

// XOR swizzle at 16B granularity, 4-bit (16-slot) spread: rows 0..15 map to 16
// DISTINCT slots (old 3-bit version aliased r and r^8 -> 8-way conflicts on the
// PV A-frag reads). P tile stays exactly 64KB. offset in bf16 elements.
__device__ __forceinline__ int swz(int row, int col){
  return row * S_LEN + ((((col >> 3) ^ row) & 15) << 3)
                     + (((col >> 3) & ~15) << 3) + (col & 7);
}

// ---- mask width detect: int32 0/1 -> every 4B word <= 1; uint8 0/1 -> words >1 whp.
__global__ void detect_mask_kernel(const unsigned int* __restrict__ m, int* __restrict__ flag){
  __shared__ int f;
  if (threadIdx.x == 0) f = 0;
  __syncthreads();
  if (m[threadIdx.x] > 1u) atomicOr(&f, 1);
  __syncthreads();
  if (threadIdx.x == 0) *flag = f;   // 0 = int32, 1 = uint8
}

// ---- K fp32 -> Kb bf16 (same layout). 8 elems/thread.
__global__ void convK_kernel(const float* __restrict__ K, unsigned short* __restrict__ Kb){
  const size_t i = ((size_t)blockIdx.x * 256 + threadIdx.x) * 8;
  floatx4 x0 = *(const floatx4*)(K + i);
  floatx4 x1 = *(const floatx4*)(K + i + 4);
  ushort8 o;
#pragma unroll
  for (int j = 0; j < 4; ++j){ o[j] = f2bf(x0[j]); o[4 + j] = f2bf(x1[j]); }
  *(ushort8*)(Kb + i) = o;
}

// ---- V fp32 -> Vt bf16 transposed: Vt[bh][n][k] (k contiguous for PV B-frags).
__global__ void vtrans_kernel(const float* __restrict__ V, unsigned short* __restrict__ Vt){
  const int bh = blockIdx.y;
  const int n  = threadIdx.x & 63;
  const int k0 = blockIdx.x * 32 + (threadIdx.x >> 6) * 8;
  const float* Vp = V + (size_t)bh * S_LEN * D_HEAD;
  ushort8 o;
#pragma unroll
  for (int i = 0; i < 8; ++i) o[i] = f2bf(Vp[(size_t)(k0 + i) * D_HEAD + n]);
  *(ushort8*)(Vt + (size_t)bh * D_HEAD * S_LEN + (size_t)n * S_LEN + k0) = o;
}

// ---- fused attention: per block = 16 q-rows x full S.
// SWAPPED QK^T: c = mfma(K_frag, Q_frag) -> D[m=score-col][n=q-row];
//   C layout (m89/m91): col=lane&15 = q-row, row=quad*4+reg = score-col.
//   => each lane owns 4 CONSECUTIVE score-cols of ONE q-row:
//      - mask read = one u32 (byte mask) / one dwordx4 (int mask) per iter
//      - P write   = one ds_write_b64 per iter (was 4x ds_write_b16)
//      - rowsum    = 2x shfl_xor (quads hold col-disjoint partials of row r16)
// Phase 2: cross-wave rowsum via redg/invg globals (LDS is 100% P tile).
// Phase 3: PV from LDS A-frags + Vt B-frags; ctx = acc * inv.
// Phase 4: prob = P * inv, ds_read_b128 + dwordx4 stores (8 elems/insn).
// Grid remap: XCD x owns heads 4x..4x+3 so K+V (2MB) stay L2-resident per XCD.
__global__ __launch_bounds__(256, 2) void attn_kernel(
    const float* __restrict__ Q, const unsigned short* __restrict__ Kb,
    const void* __restrict__ maskp, const int* __restrict__ flag,
    const unsigned short* __restrict__ Vt,
    float* __restrict__ prob, float* __restrict__ ctx,
    float* __restrict__ redg, float* __restrict__ invg){

  __shared__ unsigned short Pt[16 * S_LEN];   // exactly 64 KB

  // XCD-aware remap: hw dispatch is x-major linear, round-robin over 8 XCDs.
  const int lin  = blockIdx.y * gridDim.x + blockIdx.x;
  const int xcd  = lin & 7;
  const int sub  = lin >> 3;
  const int bh   = xcd * 4 + (sub & 3);   // bijective: 8 XCD x 4 heads x 128 qt
  const int qt   = sub >> 2;

  const int q0g  = bh * S_LEN + qt * 16;      // row index into flattened [BH*S]
  const int tid  = threadIdx.x;
  const int wave = tid >> 6;
  const int lane = tid & 63;
  const int quad = lane >> 4;
  const int r16  = lane & 15;
  const int blk  = bh * gridDim.x + qt;

  // ---- Phase 1 ----
  const float* qrow = Q + (size_t)(q0g + r16) * D_HEAD + quad * 8;
  short8 a0, a1;
  {
    floatx4 x0 = *(const floatx4*)(qrow);
    floatx4 x1 = *(const floatx4*)(qrow + 4);
    floatx4 y0 = *(const floatx4*)(qrow + 32);
    floatx4 y1 = *(const floatx4*)(qrow + 36);
#pragma unroll
    for (int j = 0; j < 4; ++j){
      a0[j] = (short)f2bf(x0[j]); a0[4 + j] = (short)f2bf(x1[j]);
      a1[j] = (short)f2bf(y0[j]); a1[4 + j] = (short)f2bf(y1[j]);
    }
  }

  const bool mInt = (*flag) == 0;
  const unsigned int*  mI = (const unsigned int*)maskp;
  const unsigned char* mB = (const unsigned char*)maskp;
  const size_t mrow = (size_t)(q0g + r16) * S_LEN;

  float racc = 0.f;

#pragma unroll 2
  for (int t = 0; t < 32; ++t){
    const int s0 = wave * 512 + t * 16;
    const unsigned short* krow = Kb + (size_t)(bh * S_LEN + s0 + r16) * D_HEAD + quad * 8;
    const short8 b0 = *(const short8*)(krow);
    const short8 b1 = *(const short8*)(krow + 32);
    unsigned int mm[4];
    if (mInt){
      const ui4 m4 = *(const ui4*)(mI + mrow + s0 + quad * 4);
#pragma unroll
      for (int i = 0; i < 4; ++i) mm[i] = m4[i];
    } else {
      const unsigned int mv = *(const unsigned int*)(mB + mrow + s0 + quad * 4);
#pragma unroll
      for (int i = 0; i < 4; ++i) mm[i] = (mv >> (8 * i)) & 0xffu;
    }
    floatx4 c = {0.f, 0.f, 0.f, 0.f};
    c = __builtin_amdgcn_mfma_f32_16x16x32_bf16(b0, a0, c, 0, 0, 0);  // swapped
    c = __builtin_amdgcn_mfma_f32_16x16x32_bf16(b1, a1, c, 0, 0, 0);
    us4 w;
#pragma unroll
    for (int i = 0; i < 4; ++i){
      // masked -> -1e4 -> exp underflows to exactly 0 in the fp32 reference too
      const float p = mm[i] ? 0.0f : __expf(c[i] * 0.125f);
      racc += p;
      w[i] = f2bf(p);
    }
    *(us4*)(&Pt[swz(r16, s0 + quad * 4)]) = w;   // 8B aligned within one 16B group
  }

  // ---- Phase 2: rowsums (quads hold disjoint col-chunks of row r16) ----
  racc += __shfl_xor(racc, 16);
  racc += __shfl_xor(racc, 32);
  if (lane < 16) redg[(size_t)blk * 64 + wave * 16 + lane] = racc;
  __syncthreads();   // P tile complete + partials visible
  if (tid < 16){
    float s = 0.f;
#pragma unroll
    for (int w = 0; w < 4; ++w) s += redg[(size_t)blk * 64 + w * 16 + tid];
    invg[(size_t)blk * 16 + tid] = (s > 0.f) ? (1.0f / s) : 0.0f;
  }
  __syncthreads();

  // ---- Phase 3: PV. wave w -> ctx cols [16w, 16w+16) ----
  float inv4[4];
#pragma unroll
  for (int i = 0; i < 4; ++i) inv4[i] = invg[(size_t)blk * 16 + quad * 4 + i];

  const unsigned short* vrow = Vt + (size_t)bh * D_HEAD * S_LEN
                                  + (size_t)(wave * 16 + r16) * S_LEN + quad * 8;
  floatx4 c = {0.f, 0.f, 0.f, 0.f};
#pragma unroll 4
  for (int kk = 0; kk < 64; ++kk){
    const short8 b = *(const short8*)(vrow + kk * 32);
    const short8 a = *(const short8*)(&Pt[swz(r16, kk * 32 + quad * 8)]);
    c = __builtin_amdgcn_mfma_f32_16x16x32_bf16(a, b, c, 0, 0, 0);
  }
#pragma unroll
  for (int i = 0; i < 4; ++i)
    ctx[(size_t)(q0g + quad * 4 + i) * D_HEAD + wave * 16 + r16] = c[i] * inv4[i];

  // ---- Phase 4: normalized prob (no barrier: Pt is read-only from here on) ----
#pragma unroll
  for (int rr = 0; rr < 4; ++rr){
    const int row = wave * 4 + rr;
    const float iv = invg[(size_t)blk * 16 + row];
    float* pg = prob + (size_t)(q0g + row) * S_LEN;
#pragma unroll
    for (int j = 0; j < 4; ++j){
      const int col = j * 512 + lane * 8;
      const ushort8 u = *(const ushort8*)(&Pt[swz(row, col)]);  // b128, conflict-free
      floatx4 o0, o1;
#pragma unroll
      for (int e = 0; e < 4; ++e){
        o0[e] = bf2f(u[e]) * iv;
        o1[e] = bf2f(u[4 + e]) * iv;
      }
      *(floatx4*)(pg + col)     = o0;
      *(floatx4*)(pg + col + 4) = o1;
    }
  }
}

extern "C" void kernel_launch(void* const* d_in, const int* in_sizes, int n_in,
                              void* d_out, int out_size, void* d_ws, size_t ws_size,
                              hipStream_t stream) {
  const float* Q = (const float*)d_in[0];
  const float* K = (const float*)d_in[1];
  const float* V = (const float*)d_in[2];
  const void*  M = d_in[3];

  float* ctx  = (float*)d_out;
  float* prob = (float*)d_out + (size_t)NBH * S_LEN * D_HEAD;

  // ws: [0,4) flag | [4KB, +1MB) redg | [+1MB, +256KB) invg | [2MB,10MB) Kb | [10MB,18MB) Vt
  int*   flag = (int*)d_ws;
  float* redg = (float*)((char*)d_ws + (1u << 12));
  float* invg = (float*)((char*)d_ws + (1u << 12) + (1u << 20));
  unsigned short* Kb = (unsigned short*)((char*)d_ws + (2u << 20));
  unsigned short* Vt = (unsigned short*)((char*)d_ws + (10u << 20));

  hipLaunchKernelGGL(detect_mask_kernel, dim3(1), dim3(256), 0, stream,
                     (const unsigned int*)M, flag);
  hipLaunchKernelGGL(convK_kernel, dim3(2048), dim3(256), 0, stream, K, Kb);
  hipLaunchKernelGGL(vtrans_kernel, dim3(S_LEN/32, NBH), dim3(256), 0, stream, V, Vt);
  hipLaunchKernelGGL(attn_kernel, dim3(S_LEN/16, NBH), dim3(256), 0, stream,
                     Q, Kb, M, flag, Vt, prob, ctx, redg, invg);
}